// Round 7
// baseline (16417.282 us; speedup 1.0000x reference)
//
#include <hip/hip_runtime.h>

#define SEQ_T 2048
#define BATCH 64

typedef _Float16 half2v __attribute__((ext_vector_type(2)));
typedef float floatx2 __attribute__((ext_vector_type(2)));

#if defined(__has_builtin)
#  if __has_builtin(__builtin_amdgcn_fdot2)
#    define HAVE_FDOT2 1
#  endif
#endif

// f16-pair dot with f32 accumulate — builtin or exact-f32 fallback.
// NOTE: inline-asm v_dot2_f32_f16 gave ~0.1 absmax on gfx950 (R4/R5) — banned.
__device__ __forceinline__ float fdot2f(half2v a, half2v b, float c) {
#ifdef HAVE_FDOT2
  return __builtin_amdgcn_fdot2(a, b, c, false);
#else
  return c + (float)a[0] * (float)b[0] + (float)a[1] * (float)b[1];
#endif
}

__device__ __forceinline__ floatx2 fma2(floatx2 a, floatx2 b, floatx2 c) {
#if __has_builtin(__builtin_elementwise_fma)
  return __builtin_elementwise_fma(a, b, c);
#else
  floatx2 r;
  r.x = __builtin_fmaf(a.x, b.x, c.x);
  r.y = __builtin_fmaf(a.y, b.y, c.y);
  return r;
#endif
}

__device__ __forceinline__ unsigned int h2u(half2v v) { return __builtin_bit_cast(unsigned int, v); }
__device__ __forceinline__ half2v u2h(unsigned int u) { return __builtin_bit_cast(half2v, u); }

// ---------------------------------------------------------------------------
// xproj GEMM (R2/R3-proven, unchanged): xp[tb][r*4+g] gate-interleaved f16.
// ---------------------------------------------------------------------------
template <int K, bool IN_F32>
__global__ __launch_bounds__(512) void xproj_gemm(
    const void* __restrict__ Xv,            // [M][K] f32 or f16
    const float* __restrict__ W,            // [512][K] f32
    const float* __restrict__ bih, const float* __restrict__ bhh,
    unsigned short* __restrict__ xp)        // [M][512] f16, gate-interleaved
{
  constexpr int MT = 64;
  const int g = threadIdx.x;
  const size_t m0 = (size_t)blockIdx.x * MT;

  __shared__ __align__(16) _Float16 xs[MT * K];

  if constexpr (IN_F32) {
    constexpr int PER = MT * K / 512;
    const float* Xf = (const float*)Xv + m0 * K + (size_t)g * PER;
    _Float16* dst = xs + g * PER;
#pragma unroll
    for (int i = 0; i < PER; i += 4) {
      float4 v = *reinterpret_cast<const float4*>(Xf + i);
      half2v h01; h01[0] = (_Float16)v.x; h01[1] = (_Float16)v.y;
      half2v h23; h23[0] = (_Float16)v.z; h23[1] = (_Float16)v.w;
      uint2 u; u.x = h2u(h01); u.y = h2u(h23);
      *reinterpret_cast<uint2*>(dst + i) = u;
    }
  } else {
    constexpr int PER = MT * K / 512;
    const unsigned short* Xh = (const unsigned short*)Xv + m0 * K + (size_t)g * PER;
#pragma unroll
    for (int i = 0; i < PER / 8; i++)
      reinterpret_cast<uint4*>(xs + g * PER)[i] = reinterpret_cast<const uint4*>(Xh)[i];
  }

  half2v wr[K / 2];
  {
    const float2* p = reinterpret_cast<const float2*>(W + (size_t)g * K);
#pragma unroll
    for (int k = 0; k < K / 2; k++) {
      float2 f = p[k];
      half2v v; v[0] = (_Float16)f.x; v[1] = (_Float16)f.y;
      wr[k] = v;
    }
  }
  const float bias = bih[g] + bhh[g];
  const int out_off = (g & 127) * 4 + (g >> 7);
  __syncthreads();

#pragma unroll 1
  for (int tb = 0; tb < MT; tb++) {
    const uint4* xv = reinterpret_cast<const uint4*>(xs + tb * K);
    float a0 = bias, a1 = 0.f, a2 = 0.f, a3 = 0.f;
#pragma unroll
    for (int i = 0; i < K / 8; i++) {
      const uint4 u = xv[i];
      a0 = fdot2f(wr[4 * i + 0], u2h(u.x), a0);
      a1 = fdot2f(wr[4 * i + 1], u2h(u.y), a1);
      a2 = fdot2f(wr[4 * i + 2], u2h(u.z), a2);
      a3 = fdot2f(wr[4 * i + 3], u2h(u.w), a3);
    }
    const float s = (a0 + a1) + (a2 + a3);
    xp[(m0 + tb) * 512 + out_off] = __builtin_bit_cast(unsigned short, (_Float16)s);
  }
}

// ---------------------------------------------------------------------------
// Recurrence, TWO batch elements per 1024-thread WG (TLP latency hiding):
// waves 0-7 -> batch blockIdx*2, waves 8-15 -> batch blockIdx*2+1.
// Per 512-thread half: identical verified R6 math (full-f32 datapath,
// quad reduce-scatter -> one activation/lane -> quad gather, skewed hbuf,
// one __syncthreads per step).
// ---------------------------------------------------------------------------
struct StepCtx {
  int ks, r, hidx;
  int li0, li1, li2, li3;
  float sc, am, ab;
  bool writer;
};

__device__ __forceinline__ float sigmoid_fast(float x) {
  return 1.f / (1.f + __expf(-x));
}

__device__ __forceinline__ void lstm_step(
    int cur, const StepCtx& cx,
    const floatx2 (&wh)[4][16], float (&hbuf)[2][144],
    unsigned short& pf, const unsigned short*& pf_ptr,
    float& c, unsigned short*& hout_ptr)
{
  // consume 2-steps-ago prefetch; immediately re-issue 2 ahead
  const float xpv = (float)__builtin_bit_cast(_Float16, pf);
  pf = *pf_ptr;
  pf_ptr += 2 * BATCH * 512;

  floatx2 a0 = {0.f, 0.f}, a1 = {0.f, 0.f}, a2 = {0.f, 0.f}, a3 = {0.f, 0.f};
  const float4* hv = reinterpret_cast<const float4*>(&hbuf[cur][cx.ks * 36]);
#pragma unroll
  for (int i = 0; i < 8; i++) {
    const float4 u = hv[i];
    floatx2 lo; lo.x = u.x; lo.y = u.y;
    floatx2 hi; hi.x = u.z; hi.y = u.w;
    a0 = fma2(wh[0][2 * i], lo, a0); a0 = fma2(wh[0][2 * i + 1], hi, a0);
    a1 = fma2(wh[1][2 * i], lo, a1); a1 = fma2(wh[1][2 * i + 1], hi, a1);
    a2 = fma2(wh[2][2 * i], lo, a2); a2 = fma2(wh[2][2 * i + 1], hi, a2);
    a3 = fma2(wh[3][2 * i], lo, a3); a3 = fma2(wh[3][2 * i + 1], hi, a3);
  }
  float b0v = a0.x + a0.y;
  float b1v = a1.x + a1.y;
  float b2v = a2.x + a2.y;
  float b3v = a3.x + a3.y;

  // quad reduce-scatter: lane ks ends with the full sum of gate ks
  const bool q0 = (cx.ks & 1) != 0, q1 = (cx.ks & 2) != 0;
  float s0 = q0 ? b0v : b1v;
  float s1 = q0 ? b2v : b3v;
  float r0 = __shfl_xor(s0, 1);
  float r1 = __shfl_xor(s1, 1);
  float kA = (q0 ? b1v : b0v) + r0;
  float kB = (q0 ? b3v : b2v) + r1;
  float s2 = q1 ? kA : kB;
  float r2 = __shfl_xor(s2, 2);
  float sum = (q1 ? kB : kA) + r2 + xpv;

  // ONE activation per lane: y = am * sigmoid(sc*sum) + ab
  float y = cx.am * sigmoid_fast(cx.sc * sum) + cx.ab;

  // all-gather activated gates across the quad
  float gi = __shfl(y, cx.li0);
  float gf = __shfl(y, cx.li1);
  float gg = __shfl(y, cx.li2);
  float go = __shfl(y, cx.li3);

  c = gf * c + gi * gg;
  float th = 2.f * sigmoid_fast(2.f * c) - 1.f;
  float h = go * th;

  if (cx.writer) {
    hbuf[cur ^ 1][cx.hidx] = h;
    *hout_ptr = __builtin_bit_cast(unsigned short, (_Float16)h);
  }
  hout_ptr += BATCH * 128;

  __syncthreads();
}

__global__ __launch_bounds__(1024, 1) void lstm_rec2(
    const float* __restrict__ Whh,          // [512][128] f32
    const unsigned short* __restrict__ xp,  // [T*B][512] f16 gate-interleaved
    unsigned short* __restrict__ hout)      // [T*B][128] f16
{
  const int tid = threadIdx.x;
  const int sub = tid >> 9;                 // which batch half of the WG
  const int stid = tid & 511;
  const int b = blockIdx.x * 2 + sub;
  const int l = stid & 63;
  const int w = stid >> 6;
  const int rr = l >> 2;
  const int ks = l & 3;
  const int r = w * 16 + rr;

  __shared__ __align__(16) float hbuf[2][2][144];  // [sub][buf][skewed 4x36]
  float (&hb)[2][144] = hbuf[sub];

  floatx2 wh[4][16];
#pragma unroll
  for (int g = 0; g < 4; g++) {
    const float4* p = reinterpret_cast<const float4*>(
        Whh + ((size_t)(g * 128 + r)) * 128 + ks * 32);
#pragma unroll
    for (int k = 0; k < 8; k++) {
      float4 f = p[k];
      floatx2 lo; lo.x = f.x; lo.y = f.y;
      floatx2 hi; hi.x = f.z; hi.y = f.w;
      wh[g][2 * k] = lo;
      wh[g][2 * k + 1] = hi;
    }
  }

  StepCtx cx;
  cx.ks = ks; cx.r = r;
  cx.hidx = (r >> 5) * 36 + (r & 31);
  const int lb = l & ~3;
  cx.li0 = lb + 0; cx.li1 = lb + 1; cx.li2 = lb + 2; cx.li3 = lb + 3;
  cx.sc = (ks == 2) ? 2.f : 1.f;
  cx.am = (ks == 2) ? 2.f : 1.f;
  cx.ab = (ks == 2) ? -1.f : 0.f;
  cx.writer = (ks == 0);

  if (stid < 144) hb[0][stid] = 0.f;

  const unsigned short* xpb = xp + (size_t)b * 512 + stid;  // stid == r*4+ks
  unsigned short pfa = xpb[0];
  unsigned short pfb = xpb[(size_t)1 * (BATCH * 512)];
  const unsigned short* pA = xpb + (size_t)2 * (BATCH * 512);
  const unsigned short* pB = xpb + (size_t)3 * (BATCH * 512);
  unsigned short* houtp = hout + (size_t)b * 128 + r;
  float c = 0.f;
  __syncthreads();

#pragma unroll 1
  for (int t = 0; t < SEQ_T; t += 2) {
    lstm_step(0, cx, wh, hb, pfa, pA, c, houtp);
    lstm_step(1, cx, wh, hb, pfb, pB, c, houtp);
  }
}

// ---------------------------------------------------------------------------
// Final linear: out[tb] = h1[tb]·wlin + blin  (R3-proven)
// ---------------------------------------------------------------------------
__global__ __launch_bounds__(256) void final_lin(
    const unsigned short* __restrict__ h1,  // [T*B][128] f16
    const float* __restrict__ Wlin, const float* __restrict__ blin,
    float* __restrict__ out)
{
  const size_t tb = (size_t)blockIdx.x * 256 + threadIdx.x;
  half2v wl[64];
  const float2* p = reinterpret_cast<const float2*>(Wlin);
#pragma unroll
  for (int k = 0; k < 64; k++) {
    float2 f = p[k];
    half2v v; v[0] = (_Float16)f.x; v[1] = (_Float16)f.y;
    wl[k] = v;
  }
  const uint4* hv = reinterpret_cast<const uint4*>(h1 + tb * 128);
  float a0 = 0.f, a1 = 0.f, a2 = 0.f, a3 = 0.f;
#pragma unroll
  for (int i = 0; i < 16; i++) {
    const uint4 u = hv[i];
    a0 = fdot2f(wl[4 * i + 0], u2h(u.x), a0);
    a1 = fdot2f(wl[4 * i + 1], u2h(u.y), a1);
    a2 = fdot2f(wl[4 * i + 2], u2h(u.z), a2);
    a3 = fdot2f(wl[4 * i + 3], u2h(u.w), a3);
  }
  out[tb] = (a0 + a1) + (a2 + a3) + blin[0];
}

extern "C" void kernel_launch(void* const* d_in, const int* in_sizes, int n_in,
                              void* d_out, int out_size, void* d_ws, size_t ws_size,
                              hipStream_t stream) {
  (void)in_sizes; (void)n_in; (void)out_size; (void)ws_size;

  const float* data = (const float*)d_in[0];
  const float* Wih0 = (const float*)d_in[1];
  const float* Whh0 = (const float*)d_in[2];
  const float* bih0 = (const float*)d_in[3];
  const float* bhh0 = (const float*)d_in[4];
  const float* Wih1 = (const float*)d_in[5];
  const float* Whh1 = (const float*)d_in[6];
  const float* bih1 = (const float*)d_in[7];
  const float* bhh1 = (const float*)d_in[8];
  const float* Wlin = (const float*)d_in[9];
  const float* blin = (const float*)d_in[10];

  // ws layout: xp 128 MiB | h0 32 MiB | h1 32 MiB
  unsigned char* ws = (unsigned char*)d_ws;
  unsigned short* xpb = (unsigned short*)ws;
  unsigned short* h0 = (unsigned short*)(ws + (size_t)128 * 1024 * 1024);
  unsigned short* h1 = (unsigned short*)(ws + (size_t)160 * 1024 * 1024);

  const int M = SEQ_T * BATCH;
  const int gemm_blocks = M / 64;

  xproj_gemm<64, true><<<dim3(gemm_blocks), dim3(512), 0, stream>>>(
      data, Wih0, bih0, bhh0, xpb);
  lstm_rec2<<<dim3(BATCH / 2), dim3(1024), 0, stream>>>(Whh0, xpb, h0);
  xproj_gemm<128, false><<<dim3(gemm_blocks), dim3(512), 0, stream>>>(
      h0, Wih1, bih1, bhh1, xpb);
  lstm_rec2<<<dim3(BATCH / 2), dim3(1024), 0, stream>>>(Whh1, xpb, h1);
  final_lin<<<dim3(M / 256), dim3(256), 0, stream>>>(h1, Wlin, blin, (float*)d_out);
}

// Round 8
// 3201.583 us; speedup vs baseline: 5.1279x; 5.1279x over previous
//
#include <hip/hip_runtime.h>

#define SEQ_T 2048
#define BATCH 64

typedef _Float16 half2v __attribute__((ext_vector_type(2)));
typedef float floatx2 __attribute__((ext_vector_type(2)));

#if defined(__has_builtin)
#  if __has_builtin(__builtin_amdgcn_fdot2)
#    define HAVE_FDOT2 1
#  endif
#endif

// f16-pair dot with f32 accumulate — builtin or exact-f32 fallback.
// NOTE: inline-asm v_dot2_f32_f16 gave ~0.1 absmax on gfx950 (R4/R5) — banned.
__device__ __forceinline__ float fdot2f(half2v a, half2v b, float c) {
#ifdef HAVE_FDOT2
  return __builtin_amdgcn_fdot2(a, b, c, false);
#else
  return c + (float)a[0] * (float)b[0] + (float)a[1] * (float)b[1];
#endif
}

__device__ __forceinline__ floatx2 fma2(floatx2 a, floatx2 b, floatx2 c) {
#if __has_builtin(__builtin_elementwise_fma)
  return __builtin_elementwise_fma(a, b, c);
#else
  floatx2 r;
  r.x = __builtin_fmaf(a.x, b.x, c.x);
  r.y = __builtin_fmaf(a.y, b.y, c.y);
  return r;
#endif
}

__device__ __forceinline__ unsigned int h2u(half2v v) { return __builtin_bit_cast(unsigned int, v); }
__device__ __forceinline__ half2v u2h(unsigned int u) { return __builtin_bit_cast(half2v, u); }

// ---------------------------------------------------------------------------
// xproj GEMM (R2/R3-proven, unchanged): xp[tb][r*4+g] gate-interleaved f16.
// ---------------------------------------------------------------------------
template <int K, bool IN_F32>
__global__ __launch_bounds__(512) void xproj_gemm(
    const void* __restrict__ Xv,            // [M][K] f32 or f16
    const float* __restrict__ W,            // [512][K] f32
    const float* __restrict__ bih, const float* __restrict__ bhh,
    unsigned short* __restrict__ xp)        // [M][512] f16, gate-interleaved
{
  constexpr int MT = 64;
  const int g = threadIdx.x;
  const size_t m0 = (size_t)blockIdx.x * MT;

  __shared__ __align__(16) _Float16 xs[MT * K];

  if constexpr (IN_F32) {
    constexpr int PER = MT * K / 512;
    const float* Xf = (const float*)Xv + m0 * K + (size_t)g * PER;
    _Float16* dst = xs + g * PER;
#pragma unroll
    for (int i = 0; i < PER; i += 4) {
      float4 v = *reinterpret_cast<const float4*>(Xf + i);
      half2v h01; h01[0] = (_Float16)v.x; h01[1] = (_Float16)v.y;
      half2v h23; h23[0] = (_Float16)v.z; h23[1] = (_Float16)v.w;
      uint2 u; u.x = h2u(h01); u.y = h2u(h23);
      *reinterpret_cast<uint2*>(dst + i) = u;
    }
  } else {
    constexpr int PER = MT * K / 512;
    const unsigned short* Xh = (const unsigned short*)Xv + m0 * K + (size_t)g * PER;
#pragma unroll
    for (int i = 0; i < PER / 8; i++)
      reinterpret_cast<uint4*>(xs + g * PER)[i] = reinterpret_cast<const uint4*>(Xh)[i];
  }

  half2v wr[K / 2];
  {
    const float2* p = reinterpret_cast<const float2*>(W + (size_t)g * K);
#pragma unroll
    for (int k = 0; k < K / 2; k++) {
      float2 f = p[k];
      half2v v; v[0] = (_Float16)f.x; v[1] = (_Float16)f.y;
      wr[k] = v;
    }
  }
  const float bias = bih[g] + bhh[g];
  const int out_off = (g & 127) * 4 + (g >> 7);
  __syncthreads();

#pragma unroll 1
  for (int tb = 0; tb < MT; tb++) {
    const uint4* xv = reinterpret_cast<const uint4*>(xs + tb * K);
    float a0 = bias, a1 = 0.f, a2 = 0.f, a3 = 0.f;
#pragma unroll
    for (int i = 0; i < K / 8; i++) {
      const uint4 u = xv[i];
      a0 = fdot2f(wr[4 * i + 0], u2h(u.x), a0);
      a1 = fdot2f(wr[4 * i + 1], u2h(u.y), a1);
      a2 = fdot2f(wr[4 * i + 2], u2h(u.z), a2);
      a3 = fdot2f(wr[4 * i + 3], u2h(u.w), a3);
    }
    const float s = (a0 + a1) + (a2 + a3);
    xp[(m0 + tb) * 512 + out_off] = __builtin_bit_cast(unsigned short, (_Float16)s);
  }
}

// ---------------------------------------------------------------------------
// Recurrence (R6-identical math; 512 threads, one WG per batch element).
// ONLY change vs R6: amdgpu_waves_per_eu(2,2) pins occupancy to 2 waves/EU
// so the allocator gets a 256-VGPR budget and keeps the 128-VGPR weight
// array RESIDENT (R6/R7 spilled it: VGPR_Count 84/64 < 128 needed).
// ---------------------------------------------------------------------------
struct StepCtx {
  int ks, r, hidx;
  int li0, li1, li2, li3;
  float sc, am, ab;
  bool writer;
};

__device__ __forceinline__ float sigmoid_fast(float x) {
  return 1.f / (1.f + __expf(-x));
}

__device__ __forceinline__ void lstm_step(
    int cur, const StepCtx& cx,
    const floatx2 (&wh)[4][16], float (&hbuf)[2][144],
    unsigned short& pf, const unsigned short*& pf_ptr,
    float& c, unsigned short*& hout_ptr)
{
  // consume 2-steps-ago prefetch; immediately re-issue 2 ahead
  const float xpv = (float)__builtin_bit_cast(_Float16, pf);
  pf = *pf_ptr;
  pf_ptr += 2 * BATCH * 512;

  floatx2 a0 = {0.f, 0.f}, a1 = {0.f, 0.f}, a2 = {0.f, 0.f}, a3 = {0.f, 0.f};
  const float4* hv = reinterpret_cast<const float4*>(&hbuf[cur][cx.ks * 36]);
#pragma unroll
  for (int i = 0; i < 8; i++) {
    const float4 u = hv[i];
    floatx2 lo; lo.x = u.x; lo.y = u.y;
    floatx2 hi; hi.x = u.z; hi.y = u.w;
    a0 = fma2(wh[0][2 * i], lo, a0); a0 = fma2(wh[0][2 * i + 1], hi, a0);
    a1 = fma2(wh[1][2 * i], lo, a1); a1 = fma2(wh[1][2 * i + 1], hi, a1);
    a2 = fma2(wh[2][2 * i], lo, a2); a2 = fma2(wh[2][2 * i + 1], hi, a2);
    a3 = fma2(wh[3][2 * i], lo, a3); a3 = fma2(wh[3][2 * i + 1], hi, a3);
  }
  float b0v = a0.x + a0.y;
  float b1v = a1.x + a1.y;
  float b2v = a2.x + a2.y;
  float b3v = a3.x + a3.y;

  // quad reduce-scatter: lane ks ends with the full sum of gate ks
  const bool q0 = (cx.ks & 1) != 0, q1 = (cx.ks & 2) != 0;
  float s0 = q0 ? b0v : b1v;
  float s1 = q0 ? b2v : b3v;
  float r0 = __shfl_xor(s0, 1);
  float r1 = __shfl_xor(s1, 1);
  float kA = (q0 ? b1v : b0v) + r0;
  float kB = (q0 ? b3v : b2v) + r1;
  float s2 = q1 ? kA : kB;
  float r2 = __shfl_xor(s2, 2);
  float sum = (q1 ? kB : kA) + r2 + xpv;

  // ONE activation per lane: y = am * sigmoid(sc*sum) + ab
  float y = cx.am * sigmoid_fast(cx.sc * sum) + cx.ab;

  // all-gather activated gates across the quad
  float gi = __shfl(y, cx.li0);
  float gf = __shfl(y, cx.li1);
  float gg = __shfl(y, cx.li2);
  float go = __shfl(y, cx.li3);

  c = gf * c + gi * gg;
  float th = 2.f * sigmoid_fast(2.f * c) - 1.f;
  float h = go * th;

  if (cx.writer) {
    hbuf[cur ^ 1][cx.hidx] = h;
    *hout_ptr = __builtin_bit_cast(unsigned short, (_Float16)h);
  }
  hout_ptr += BATCH * 128;

  __syncthreads();
}

__global__ __launch_bounds__(512)
__attribute__((amdgpu_waves_per_eu(2, 2)))
void lstm_rec2(
    const float* __restrict__ Whh,          // [512][128] f32
    const unsigned short* __restrict__ xp,  // [T*B][512] f16 gate-interleaved
    unsigned short* __restrict__ hout)      // [T*B][128] f16
{
  const int b = blockIdx.x;
  const int tid = threadIdx.x;
  const int l = tid & 63;
  const int w = tid >> 6;
  const int rr = l >> 2;
  const int ks = l & 3;
  const int r = w * 16 + rr;

  __shared__ __align__(16) float hbuf[2][144];   // 4 chunks x 36 (skewed)

  // Whh rows for this thread's 4 gates, chunk ks*32..+32, as f32 pairs
  floatx2 wh[4][16];
#pragma unroll
  for (int g = 0; g < 4; g++) {
    const float4* p = reinterpret_cast<const float4*>(
        Whh + ((size_t)(g * 128 + r)) * 128 + ks * 32);
#pragma unroll
    for (int k = 0; k < 8; k++) {
      float4 f = p[k];
      floatx2 lo; lo.x = f.x; lo.y = f.y;
      floatx2 hi; hi.x = f.z; hi.y = f.w;
      wh[g][2 * k] = lo;
      wh[g][2 * k + 1] = hi;
    }
  }

  StepCtx cx;
  cx.ks = ks; cx.r = r;
  cx.hidx = (r >> 5) * 36 + (r & 31);
  const int lb = l & ~3;
  cx.li0 = lb + 0; cx.li1 = lb + 1; cx.li2 = lb + 2; cx.li3 = lb + 3;
  cx.sc = (ks == 2) ? 2.f : 1.f;
  cx.am = (ks == 2) ? 2.f : 1.f;
  cx.ab = (ks == 2) ? -1.f : 0.f;
  cx.writer = (ks == 0);

  if (tid < 144) { hbuf[0][tid] = 0.f; }

  const unsigned short* xpb = xp + (size_t)b * 512 + tid;  // tid == r*4+ks
  unsigned short pfa = xpb[0];
  unsigned short pfb = xpb[(size_t)1 * (BATCH * 512)];
  const unsigned short* pA = xpb + (size_t)2 * (BATCH * 512);
  const unsigned short* pB = xpb + (size_t)3 * (BATCH * 512);
  unsigned short* houtp = hout + (size_t)b * 128 + r;
  float c = 0.f;
  __syncthreads();

#pragma unroll 1
  for (int t = 0; t < SEQ_T; t += 2) {
    lstm_step(0, cx, wh, hbuf, pfa, pA, c, houtp);
    lstm_step(1, cx, wh, hbuf, pfb, pB, c, houtp);
  }
}

// ---------------------------------------------------------------------------
// Final linear: out[tb] = h1[tb]·wlin + blin  (R3-proven)
// ---------------------------------------------------------------------------
__global__ __launch_bounds__(256) void final_lin(
    const unsigned short* __restrict__ h1,  // [T*B][128] f16
    const float* __restrict__ Wlin, const float* __restrict__ blin,
    float* __restrict__ out)
{
  const size_t tb = (size_t)blockIdx.x * 256 + threadIdx.x;
  half2v wl[64];
  const float2* p = reinterpret_cast<const float2*>(Wlin);
#pragma unroll
  for (int k = 0; k < 64; k++) {
    float2 f = p[k];
    half2v v; v[0] = (_Float16)f.x; v[1] = (_Float16)f.y;
    wl[k] = v;
  }
  const uint4* hv = reinterpret_cast<const uint4*>(h1 + tb * 128);
  float a0 = 0.f, a1 = 0.f, a2 = 0.f, a3 = 0.f;
#pragma unroll
  for (int i = 0; i < 16; i++) {
    const uint4 u = hv[i];
    a0 = fdot2f(wl[4 * i + 0], u2h(u.x), a0);
    a1 = fdot2f(wl[4 * i + 1], u2h(u.y), a1);
    a2 = fdot2f(wl[4 * i + 2], u2h(u.z), a2);
    a3 = fdot2f(wl[4 * i + 3], u2h(u.w), a3);
  }
  out[tb] = (a0 + a1) + (a2 + a3) + blin[0];
}

extern "C" void kernel_launch(void* const* d_in, const int* in_sizes, int n_in,
                              void* d_out, int out_size, void* d_ws, size_t ws_size,
                              hipStream_t stream) {
  (void)in_sizes; (void)n_in; (void)out_size; (void)ws_size;

  const float* data = (const float*)d_in[0];
  const float* Wih0 = (const float*)d_in[1];
  const float* Whh0 = (const float*)d_in[2];
  const float* bih0 = (const float*)d_in[3];
  const float* bhh0 = (const float*)d_in[4];
  const float* Wih1 = (const float*)d_in[5];
  const float* Whh1 = (const float*)d_in[6];
  const float* bih1 = (const float*)d_in[7];
  const float* bhh1 = (const float*)d_in[8];
  const float* Wlin = (const float*)d_in[9];
  const float* blin = (const float*)d_in[10];

  // ws layout: xp 128 MiB | h0 32 MiB | h1 32 MiB
  unsigned char* ws = (unsigned char*)d_ws;
  unsigned short* xpb = (unsigned short*)ws;
  unsigned short* h0 = (unsigned short*)(ws + (size_t)128 * 1024 * 1024);
  unsigned short* h1 = (unsigned short*)(ws + (size_t)160 * 1024 * 1024);

  const int M = SEQ_T * BATCH;
  const int gemm_blocks = M / 64;

  xproj_gemm<64, true><<<dim3(gemm_blocks), dim3(512), 0, stream>>>(
      data, Wih0, bih0, bhh0, xpb);
  lstm_rec2<<<dim3(BATCH), dim3(512), 0, stream>>>(Whh0, xpb, h0);
  xproj_gemm<128, false><<<dim3(gemm_blocks), dim3(512), 0, stream>>>(
      h0, Wih1, bih1, bhh1, xpb);
  lstm_rec2<<<dim3(BATCH), dim3(512), 0, stream>>>(Whh1, xpb, h1);
  final_lin<<<dim3(M / 256), dim3(256), 0, stream>>>(h1, Wlin, blin, (float*)d_out);
}

// Round 9
// 2752.247 us; speedup vs baseline: 5.9650x; 1.1633x over previous
//
#include <hip/hip_runtime.h>

#define SEQ_T 2048
#define BATCH 64

typedef _Float16 half2v __attribute__((ext_vector_type(2)));
typedef float floatx2 __attribute__((ext_vector_type(2)));

#if defined(__has_builtin)
#  if __has_builtin(__builtin_amdgcn_fdot2)
#    define HAVE_FDOT2 1
#  endif
#endif

// f16-pair dot with f32 accumulate — builtin or exact-f32 fallback.
// NOTE: inline-asm v_dot2_f32_f16 gave ~0.1 absmax on gfx950 (R4/R5) — banned.
__device__ __forceinline__ float fdot2f(half2v a, half2v b, float c) {
#ifdef HAVE_FDOT2
  return __builtin_amdgcn_fdot2(a, b, c, false);
#else
  return c + (float)a[0] * (float)b[0] + (float)a[1] * (float)b[1];
#endif
}

__device__ __forceinline__ unsigned int h2u(half2v v) { return __builtin_bit_cast(unsigned int, v); }
__device__ __forceinline__ half2v u2h(unsigned int u) { return __builtin_bit_cast(half2v, u); }

// Within-quad lane permute on the VALU (DPP quad_perm) — no LDS pipe.
template <int CTRL>
__device__ __forceinline__ float qperm(float x) {
  int xi = __builtin_bit_cast(int, x);
  int ri = __builtin_amdgcn_update_dpp(xi, xi, CTRL, 0xF, 0xF, true);
  return __builtin_bit_cast(float, ri);
}
#define QP_XOR1 0xB1  // [1,0,3,2]
#define QP_XOR2 0x4E  // [2,3,0,1]
#define QP_B0   0x00
#define QP_B1   0x55
#define QP_B2   0xAA
#define QP_B3   0xFF

// ---------------------------------------------------------------------------
// xproj GEMM (R2/R3-proven, unchanged): xp[tb][r*4+g] gate-interleaved f16.
// ---------------------------------------------------------------------------
template <int K, bool IN_F32>
__global__ __launch_bounds__(512) void xproj_gemm(
    const void* __restrict__ Xv,            // [M][K] f32 or f16
    const float* __restrict__ W,            // [512][K] f32
    const float* __restrict__ bih, const float* __restrict__ bhh,
    unsigned short* __restrict__ xp)        // [M][512] f16, gate-interleaved
{
  constexpr int MT = 64;
  const int g = threadIdx.x;
  const size_t m0 = (size_t)blockIdx.x * MT;

  __shared__ __align__(16) _Float16 xs[MT * K];

  if constexpr (IN_F32) {
    constexpr int PER = MT * K / 512;
    const float* Xf = (const float*)Xv + m0 * K + (size_t)g * PER;
    _Float16* dst = xs + g * PER;
#pragma unroll
    for (int i = 0; i < PER; i += 4) {
      float4 v = *reinterpret_cast<const float4*>(Xf + i);
      half2v h01; h01[0] = (_Float16)v.x; h01[1] = (_Float16)v.y;
      half2v h23; h23[0] = (_Float16)v.z; h23[1] = (_Float16)v.w;
      uint2 u; u.x = h2u(h01); u.y = h2u(h23);
      *reinterpret_cast<uint2*>(dst + i) = u;
    }
  } else {
    constexpr int PER = MT * K / 512;
    const unsigned short* Xh = (const unsigned short*)Xv + m0 * K + (size_t)g * PER;
#pragma unroll
    for (int i = 0; i < PER / 8; i++)
      reinterpret_cast<uint4*>(xs + g * PER)[i] = reinterpret_cast<const uint4*>(Xh)[i];
  }

  half2v wr[K / 2];
  {
    const float2* p = reinterpret_cast<const float2*>(W + (size_t)g * K);
#pragma unroll
    for (int k = 0; k < K / 2; k++) {
      float2 f = p[k];
      half2v v; v[0] = (_Float16)f.x; v[1] = (_Float16)f.y;
      wr[k] = v;
    }
  }
  const float bias = bih[g] + bhh[g];
  const int out_off = (g & 127) * 4 + (g >> 7);
  __syncthreads();

#pragma unroll 1
  for (int tb = 0; tb < MT; tb++) {
    const uint4* xv = reinterpret_cast<const uint4*>(xs + tb * K);
    float a0 = bias, a1 = 0.f, a2 = 0.f, a3 = 0.f;
#pragma unroll
    for (int i = 0; i < K / 8; i++) {
      const uint4 u = xv[i];
      a0 = fdot2f(wr[4 * i + 0], u2h(u.x), a0);
      a1 = fdot2f(wr[4 * i + 1], u2h(u.y), a1);
      a2 = fdot2f(wr[4 * i + 2], u2h(u.z), a2);
      a3 = fdot2f(wr[4 * i + 3], u2h(u.w), a3);
    }
    const float s = (a0 + a1) + (a2 + a3);
    xp[(m0 + tb) * 512 + out_off] = __builtin_bit_cast(unsigned short, (_Float16)s);
  }
}

// ---------------------------------------------------------------------------
// Recurrence (R6 structure; 512 threads, one WG per batch element).
// R9 changes vs R8:
//  (1) all cross-lane ops -> DPP quad_perm (VALU) instead of __shfl (LDS pipe)
//  (2) weights stored as f16 pairs (64 VGPRs, fma_mix f32-accumulate) so the
//      allocator keeps them RESIDENT (f32 version rematerialized per step).
// ---------------------------------------------------------------------------
struct StepCtx {
  int ks, r, hidx;
  float sc, am, ab;
  bool writer;
};

__device__ __forceinline__ float sigmoid_fast(float x) {
  return 1.f / (1.f + __expf(-x));
}

__device__ __forceinline__ void lstm_step(
    int cur, const StepCtx& cx,
    const half2v (&wh)[4][16], float (&hbuf)[2][144],
    unsigned short& pf, const unsigned short*& pf_ptr,
    float& c, unsigned short*& hout_ptr)
{
  // consume 2-steps-ago prefetch; immediately re-issue 2 ahead
  const float xpv = (float)__builtin_bit_cast(_Float16, pf);
  pf = *pf_ptr;
  pf_ptr += 2 * BATCH * 512;

  float a0 = 0.f, a1 = 0.f, a2 = 0.f, a3 = 0.f;
  const float4* hv = reinterpret_cast<const float4*>(&hbuf[cur][cx.ks * 36]);
#pragma unroll
  for (int i = 0; i < 8; i++) {
    const float4 u = hv[i];
    {
      const half2v wa = wh[0][2 * i], wb = wh[0][2 * i + 1];
      a0 = fmaf((float)wa[0], u.x, a0); a0 = fmaf((float)wa[1], u.y, a0);
      a0 = fmaf((float)wb[0], u.z, a0); a0 = fmaf((float)wb[1], u.w, a0);
    }
    {
      const half2v wa = wh[1][2 * i], wb = wh[1][2 * i + 1];
      a1 = fmaf((float)wa[0], u.x, a1); a1 = fmaf((float)wa[1], u.y, a1);
      a1 = fmaf((float)wb[0], u.z, a1); a1 = fmaf((float)wb[1], u.w, a1);
    }
    {
      const half2v wa = wh[2][2 * i], wb = wh[2][2 * i + 1];
      a2 = fmaf((float)wa[0], u.x, a2); a2 = fmaf((float)wa[1], u.y, a2);
      a2 = fmaf((float)wb[0], u.z, a2); a2 = fmaf((float)wb[1], u.w, a2);
    }
    {
      const half2v wa = wh[3][2 * i], wb = wh[3][2 * i + 1];
      a3 = fmaf((float)wa[0], u.x, a3); a3 = fmaf((float)wa[1], u.y, a3);
      a3 = fmaf((float)wb[0], u.z, a3); a3 = fmaf((float)wb[1], u.w, a3);
    }
  }

  // quad reduce-scatter via DPP: lane ks ends with the full sum of gate ks
  const bool q0 = (cx.ks & 1) != 0, q1 = (cx.ks & 2) != 0;
  float s0 = q0 ? a0 : a1;
  float s1 = q0 ? a2 : a3;
  float r0 = qperm<QP_XOR1>(s0);
  float r1 = qperm<QP_XOR1>(s1);
  float kA = (q0 ? a1 : a0) + r0;
  float kB = (q0 ? a3 : a2) + r1;
  float s2 = q1 ? kA : kB;
  float r2 = qperm<QP_XOR2>(s2);
  float sum = (q1 ? kB : kA) + r2 + xpv;

  // ONE activation per lane: y = am * sigmoid(sc*sum) + ab
  float y = cx.am * sigmoid_fast(cx.sc * sum) + cx.ab;

  // all-gather activated gates across the quad via DPP broadcasts
  float gi = qperm<QP_B0>(y);
  float gf = qperm<QP_B1>(y);
  float gg = qperm<QP_B2>(y);
  float go = qperm<QP_B3>(y);

  c = gf * c + gi * gg;
  float th = 2.f * sigmoid_fast(2.f * c) - 1.f;
  float h = go * th;

  if (cx.writer) {
    hbuf[cur ^ 1][cx.hidx] = h;
    *hout_ptr = __builtin_bit_cast(unsigned short, (_Float16)h);
  }
  hout_ptr += BATCH * 128;

  __syncthreads();
}

__global__ __launch_bounds__(512)
__attribute__((amdgpu_waves_per_eu(2, 2)))
void lstm_rec2(
    const float* __restrict__ Whh,          // [512][128] f32
    const unsigned short* __restrict__ xp,  // [T*B][512] f16 gate-interleaved
    unsigned short* __restrict__ hout)      // [T*B][128] f16
{
  const int b = blockIdx.x;
  const int tid = threadIdx.x;
  const int l = tid & 63;
  const int w = tid >> 6;
  const int rr = l >> 2;
  const int ks = l & 3;
  const int r = w * 16 + rr;

  __shared__ __align__(16) float hbuf[2][144];   // 4 chunks x 36 (skewed)

  // Whh rows for this thread's 4 gates, chunk ks*32..+32, as f16 pairs (64 VGPR)
  half2v wh[4][16];
#pragma unroll
  for (int g = 0; g < 4; g++) {
    const float4* p = reinterpret_cast<const float4*>(
        Whh + ((size_t)(g * 128 + r)) * 128 + ks * 32);
#pragma unroll
    for (int k = 0; k < 8; k++) {
      float4 f = p[k];
      half2v lo; lo[0] = (_Float16)f.x; lo[1] = (_Float16)f.y;
      half2v hi; hi[0] = (_Float16)f.z; hi[1] = (_Float16)f.w;
      wh[g][2 * k] = lo;
      wh[g][2 * k + 1] = hi;
    }
  }

  StepCtx cx;
  cx.ks = ks; cx.r = r;
  cx.hidx = (r >> 5) * 36 + (r & 31);
  cx.sc = (ks == 2) ? 2.f : 1.f;
  cx.am = (ks == 2) ? 2.f : 1.f;
  cx.ab = (ks == 2) ? -1.f : 0.f;
  cx.writer = (ks == 0);

  if (tid < 144) { hbuf[0][tid] = 0.f; }

  const unsigned short* xpb = xp + (size_t)b * 512 + tid;  // tid == r*4+ks
  unsigned short pfa = xpb[0];
  unsigned short pfb = xpb[(size_t)1 * (BATCH * 512)];
  const unsigned short* pA = xpb + (size_t)2 * (BATCH * 512);
  const unsigned short* pB = xpb + (size_t)3 * (BATCH * 512);
  unsigned short* houtp = hout + (size_t)b * 128 + r;
  float c = 0.f;
  __syncthreads();

#pragma unroll 1
  for (int t = 0; t < SEQ_T; t += 2) {
    lstm_step(0, cx, wh, hbuf, pfa, pA, c, houtp);
    lstm_step(1, cx, wh, hbuf, pfb, pB, c, houtp);
  }
}

// ---------------------------------------------------------------------------
// Final linear: out[tb] = h1[tb]·wlin + blin  (R3-proven)
// ---------------------------------------------------------------------------
__global__ __launch_bounds__(256) void final_lin(
    const unsigned short* __restrict__ h1,  // [T*B][128] f16
    const float* __restrict__ Wlin, const float* __restrict__ blin,
    float* __restrict__ out)
{
  const size_t tb = (size_t)blockIdx.x * 256 + threadIdx.x;
  half2v wl[64];
  const float2* p = reinterpret_cast<const float2*>(Wlin);
#pragma unroll
  for (int k = 0; k < 64; k++) {
    float2 f = p[k];
    half2v v; v[0] = (_Float16)f.x; v[1] = (_Float16)f.y;
    wl[k] = v;
  }
  const uint4* hv = reinterpret_cast<const uint4*>(h1 + tb * 128);
  float a0 = 0.f, a1 = 0.f, a2 = 0.f, a3 = 0.f;
#pragma unroll
  for (int i = 0; i < 16; i++) {
    const uint4 u = hv[i];
    a0 = fdot2f(wl[4 * i + 0], u2h(u.x), a0);
    a1 = fdot2f(wl[4 * i + 1], u2h(u.y), a1);
    a2 = fdot2f(wl[4 * i + 2], u2h(u.z), a2);
    a3 = fdot2f(wl[4 * i + 3], u2h(u.w), a3);
  }
  out[tb] = (a0 + a1) + (a2 + a3) + blin[0];
}

extern "C" void kernel_launch(void* const* d_in, const int* in_sizes, int n_in,
                              void* d_out, int out_size, void* d_ws, size_t ws_size,
                              hipStream_t stream) {
  (void)in_sizes; (void)n_in; (void)out_size; (void)ws_size;

  const float* data = (const float*)d_in[0];
  const float* Wih0 = (const float*)d_in[1];
  const float* Whh0 = (const float*)d_in[2];
  const float* bih0 = (const float*)d_in[3];
  const float* bhh0 = (const float*)d_in[4];
  const float* Wih1 = (const float*)d_in[5];
  const float* Whh1 = (const float*)d_in[6];
  const float* bih1 = (const float*)d_in[7];
  const float* bhh1 = (const float*)d_in[8];
  const float* Wlin = (const float*)d_in[9];
  const float* blin = (const float*)d_in[10];

  // ws layout: xp 128 MiB | h0 32 MiB | h1 32 MiB
  unsigned char* ws = (unsigned char*)d_ws;
  unsigned short* xpb = (unsigned short*)ws;
  unsigned short* h0 = (unsigned short*)(ws + (size_t)128 * 1024 * 1024);
  unsigned short* h1 = (unsigned short*)(ws + (size_t)160 * 1024 * 1024);

  const int M = SEQ_T * BATCH;
  const int gemm_blocks = M / 64;

  xproj_gemm<64, true><<<dim3(gemm_blocks), dim3(512), 0, stream>>>(
      data, Wih0, bih0, bhh0, xpb);
  lstm_rec2<<<dim3(BATCH), dim3(512), 0, stream>>>(Whh0, xpb, h0);
  xproj_gemm<128, false><<<dim3(gemm_blocks), dim3(512), 0, stream>>>(
      h0, Wih1, bih1, bhh1, xpb);
  lstm_rec2<<<dim3(BATCH), dim3(512), 0, stream>>>(Whh1, xpb, h1);
  final_lin<<<dim3(M / 256), dim3(256), 0, stream>>>(h1, Wlin, blin, (float*)d_out);
}